// Round 13
// baseline (7325.425 us; speedup 1.0000x reference)
//
#include <hip/hip_runtime.h>

#define BB 256
#define TT 512
#define HH 512
#define NTH 512
#define SLOTP 65536        // u32x4 granules per ping-pong slot (256 b x 256 pairs)
#define SPIN_CAP (1 << 14) // terminate pathological spins (fail-visible, not hang)

typedef float    f32x4 __attribute__((ext_vector_type(4)));
typedef float    f32x2 __attribute__((ext_vector_type(2)));
typedef unsigned u32x4 __attribute__((ext_vector_type(4)));
typedef unsigned u32x2 __attribute__((ext_vector_type(2)));
typedef short    bf16x8 __attribute__((ext_vector_type(8)));

__device__ __forceinline__ f32x4 mfma16(u32x4 a, u32x4 b, f32x4 c) {
    return __builtin_amdgcn_mfma_f32_16x16x32_bf16(
        __builtin_bit_cast(bf16x8, a), __builtin_bit_cast(bf16x8, b), c, 0, 0, 0);
}
__device__ __forceinline__ unsigned rne16(float f) {
    unsigned u = __builtin_bit_cast(unsigned, f);
    return (u + 0x7FFFu + ((u >> 16) & 1u)) >> 16;
}

// frag range [F0,F1): 2 ds_read_b128 + 3 MFMA per frag (3 indep chains)
#define PH(F0, F1, HIp, LOp, Ch, Cd, Ce)                                       \
    { _Pragma("unroll")                                                        \
      for (int f = (F0); f < (F1); ++f) {                                      \
          const int kb = (4 * q + f) & 15;                                     \
          u32x4 bh = *reinterpret_cast<const u32x4*>(&(HIp)[kb * 256 + l * 4]);\
          u32x4 bl = *reinterpret_cast<const u32x4*>(&(LOp)[kb * 256 + l * 4]);\
          Ch = mfma16(Ahi[f], bh, Ch);                                         \
          Cd = mfma16(Ahi[f], bl, Cd);                                         \
          Ce = mfma16(Alo[f], bh, Ce);                                         \
      } }

#define ISSUE6(G, BASE)                                                        \
    { _Pragma("unroll")                                                        \
      for (int jx = 0; jx < 6; ++jx)                                           \
          asm volatile("global_load_dwordx4 %0, %1, off sc0 sc1"               \
                       : "=&v"((G)[jx]) : "v"((BASE) + goff[jx]) : "memory"); }

// one half-step of stream S: spin+land -> phase2 -> epilogue -> phase1(t+1) -> issue(t+1)
#define HS(G, Ch, Cd, Ce, HIp, LOp, B0S)                                       \
    {                                                                          \
        const unsigned Tg = (unsigned)t, T1u = Tg + 1u;                        \
        u32x4* basec = xch + (size_t)(t & 1) * SLOTP + (size_t)(B0S) * 256;    \
        u32x4* basen = xch + (size_t)((t + 1) & 1) * SLOTP + (size_t)(B0S) * 256; \
        if (t > 0) {                                                           \
            int guard = 0;                                                     \
            for (;;) {                                                         \
                asm volatile("s_waitcnt vmcnt(0)" ::: "memory");               \
                __builtin_amdgcn_sched_barrier(0);                             \
                int ok = 1;                                                    \
                _Pragma("unroll")                                              \
                for (int jx = 0; jx < 6; ++jx)                                 \
                    ok &= (int)((G)[jx].z == Tg) & (int)((G)[jx].w == Tg);     \
                if (__all(ok) || ++guard > SPIN_CAP) break;                    \
                ISSUE6(G, basec)                                               \
            }                                                                  \
            _Pragma("unroll")                                                  \
            for (int jx = 0; jx < 6; ++jx) {                                   \
                (HIp)[ldd[jx]] = (G)[jx].x;                                    \
                (LOp)[ldd[jx]] = (G)[jx].y;                                    \
            }                                                                  \
        }                                                                      \
        __syncthreads(); /* staged h(t) complete */                            \
        PH(4, 16, HIp, LOp, Ch, Cd, Ce)                                        \
        {                                                                      \
            f32x4 C = Ch + Cd + Ce;                                            \
            f32x2 xv = *reinterpret_cast<const f32x2*>(                        \
                x + (size_t)((B0S) + col) * (TT * 2) + 2 * t);                 \
            f32x4 v;                                                           \
            unsigned h_[4], l_[4];                                             \
            _Pragma("unroll")                                                  \
            for (int r = 0; r < 4; ++r) {                                      \
                v[r] = fmaxf(C[r] + wxa[r] * xv[0] + wxb[r] * xv[1], 0.f);     \
                h_[r] = rne16(v[r]);                                           \
                l_[r] = rne16(v[r] - __builtin_bit_cast(float, h_[r] << 16));  \
            }                                                                  \
            const unsigned H0 = h_[0] | (h_[1] << 16), L0 = l_[0] | (l_[1] << 16); \
            const unsigned H1 = h_[2] | (h_[3] << 16), L1 = l_[2] | (l_[3] << 16); \
            u32x4 ga = {H0, L0, T1u, T1u}, gb = {H1, L1, T1u, T1u};            \
            u32x4* pd = xch + (size_t)((t + 1) & 1) * SLOTP                    \
                        + (size_t)((B0S) + col) * 256 + (j0 >> 1);             \
            asm volatile("global_store_dwordx4 %0, %2, off sc0 sc1\n\t"        \
                         "global_store_dwordx4 %1, %3, off sc0 sc1"            \
                         :: "v"(pd), "v"(pd + 1), "v"(ga), "v"(gb) : "memory");\
            *reinterpret_cast<u32x2*>(&(HIp)[d0own]) = u32x2{H0, H1};          \
            *reinterpret_cast<u32x2*>(&(LOp)[d0own]) = u32x2{L0, L1};          \
            *reinterpret_cast<f32x4*>(out + (size_t)(t + 1) * (BB * HH)        \
                + (size_t)((B0S) + col) * HH + j0) = v;                        \
        }                                                                      \
        __syncthreads(); /* own-quarter of next buf staged */                  \
        if (t + 1 < TT) {                                                      \
            Ch = Z; Cd = Z; Ce = Z;                                            \
            PH(0, 4, HIp, LOp, Ch, Cd, Ce)                                     \
            ISSUE6(G, basen)  /* never leave dangling loads at s_endpgm */     \
        }                                                                      \
    }

// Half-step dual-stream quad-split MFMA RNN (bf16-split fp32 emulation,
// hi*hi + hi*lo + lo*hi; RNE splits). 8 quads x 4 WGs = 32 WGs x 512 thr
// (8 waves = 8 m-tiles of 16 rows). WG q owns j-rows [128q,+128) for two
// independent 16-batch streams (A: batches grp*32.., B: +16); streams
// alternate half-steps so each stream's L3 exchange latency hides under the
// other stream's compute. Exchange protocol/layout identical to R10
// (field-validated): 16B granules (hi-pair, lo-pair, tag, tag), ping-pong
// slots by t&1, sc0sc1 L3-coherent, frag-linear LDS staging, own quarter
// staged locally (never leaves the CU). Spin-capped: protocol failure shows
// as absmax + counters, never a hang.
__global__ void __attribute__((amdgpu_flat_work_group_size(NTH, NTH)))
rnn_hs(const float* __restrict__ x,    // [B, T, 2]
       const float* __restrict__ Wh,   // [H, H]
       const float* __restrict__ Wx,   // [H, 2]
       float* __restrict__ out,        // [T+1, B, H]
       u32x4* __restrict__ xch)        // [2][256][256] granules (2 MB)
{
    const int bid = blockIdx.x, tid = threadIdx.x;
    const int q = bid & 3, grp = bid >> 2;
    const int b0A = grp * 32, b0B = b0A + 16;
    const int wid = tid >> 6, l = tid & 63;
    const int col = l & 15, qr = l >> 4;
    const int J0 = 128 * q;

    __shared__ unsigned SHI[2][4096];    // hi-plane staging, frag-linear (16 KB ea)
    __shared__ unsigned SLO[2][4096];    // lo-plane

    // ---- A-frags: wave wid owns m-tile rows J0+wid*16; rotation-indexed
    //      frag f <-> global k-block (4q+f)&15 (f=0..3 own quarter) ----
    u32x4 Ahi[16], Alo[16];
    {
        const float* rp = Wh + (size_t)(J0 + wid * 16 + col) * HH + qr * 8;
        #pragma unroll
        for (int f = 0; f < 16; ++f) {
            const int kb = (4 * q + f) & 15;
            const f32x4* p = reinterpret_cast<const f32x4*>(rp + kb * 32);
            f32x4 v0 = p[0], v1 = p[1];
            float fv[8] = {v0[0], v0[1], v0[2], v0[3], v1[0], v1[1], v1[2], v1[3]};
            u32x4 hi, lo;
            #pragma unroll
            for (int r = 0; r < 4; ++r) {
                unsigned h0 = rne16(fv[2*r]);
                unsigned l0 = rne16(fv[2*r]   - __builtin_bit_cast(float, h0 << 16));
                unsigned h1 = rne16(fv[2*r+1]);
                unsigned l1 = rne16(fv[2*r+1] - __builtin_bit_cast(float, h1 << 16));
                hi[r] = h0 | (h1 << 16);
                lo[r] = l0 | (l1 << 16);
            }
            Ahi[f] = hi; Alo[f] = lo;
        }
    }

    // ---- per-lane epilogue identity: rows j0..j0+3, batch = col ----
    const int j0 = J0 + wid * 16 + qr * 4;
    const int d0own = (j0 >> 5) * 256 + ((j0 >> 3) & 3) * 64 + col * 4 + ((j0 & 7) >> 1);
    float wxa[4], wxb[4];
    #pragma unroll
    for (int r = 0; r < 4; ++r) { wxa[r] = Wx[2 * (j0 + r)]; wxb[r] = Wx[2 * (j0 + r) + 1]; }

    // ---- zero staging; out[0] for own quarter x 32 batches ----
    {
        u32x4 zz = {0u, 0u, 0u, 0u};
        #pragma unroll
        for (int it = 0; it < 4; ++it) {
            reinterpret_cast<u32x4*>(SHI)[it * 512 + tid] = zz;
            reinterpret_cast<u32x4*>(SLO)[it * 512 + tid] = zz;
        }
    }
    #pragma unroll
    for (int it = 0; it < 2; ++it) {
        int idx = it * 512 + tid;             // 1024 = 32 b x 32 j-quads
        int b32 = idx >> 5, j4 = (idx & 31) * 4;
        f32x4 z; z[0] = (J0 + j4 == 0) ? 1.f : 0.f; z[1] = 0.f; z[2] = 0.f; z[3] = 0.f;
        *reinterpret_cast<f32x4*>(out + (size_t)(b0A + b32) * HH + J0 + j4) = z;
    }
    __syncthreads();
    if (tid < 16) {                           // h0: bf16(1.0) at k=0, all 16 b, both streams
        SHI[0][tid * 4] = 0x3F80u;
        SHI[1][tid * 4] = 0x3F80u;
    }

    // ---- loader map: 6 remote granules/thread/stream ----
    int goff[6], ldd[6];
    {
        const int lb = tid & 15, sub = tid >> 4;       // batch, 0..31
        #pragma unroll
        for (int jx = 0; jx < 6; ++jx) {
            const int Qq = (q + 1 + (jx >> 1)) & 3;
            const int kp = (jx & 1) * 32 + sub;        // granule in quarter, 0..63
            goff[jx] = lb * 256 + Qq * 64 + kp;
            const int jv = Qq * 128 + kp * 2;
            ldd[jx] = (jv >> 5) * 256 + ((jv >> 3) & 3) * 64 + lb * 4 + ((jv & 7) >> 1);
        }
    }
    __syncthreads();

    // ---- prologue: phase1 of t=0 for both streams ----
    const f32x4 Z = {0.f, 0.f, 0.f, 0.f};
    f32x4 CAh = Z, CAd = Z, CAe = Z, CBh = Z, CBd = Z, CBe = Z;
    PH(0, 4, SHI[0], SLO[0], CAh, CAd, CAe)
    PH(0, 4, SHI[1], SLO[1], CBh, CBd, CBe)

    u32x4 gA[6], gB[6];
    for (int h = 0; h < 2 * TT; ++h) {
        const int t = h >> 1;
        if ((h & 1) == 0) {
            HS(gA, CAh, CAd, CAe, SHI[0], SLO[0], b0A)
        } else {
            HS(gB, CBh, CBd, CBe, SHI[1], SLO[1], b0B)
        }
    }
}

extern "C" void kernel_launch(void* const* d_in, const int* in_sizes, int n_in,
                              void* d_out, int out_size, void* d_ws, size_t ws_size,
                              hipStream_t stream) {
    const float* x  = (const float*)d_in[0];
    const float* Wh = (const float*)d_in[1];
    const float* Wx = (const float*)d_in[2];
    float* out = (float*)d_out;
    u32x4* xch = (u32x4*)d_ws;    // 2 slots * 65536 granules * 16B = 2 MB
    rnn_hs<<<32, NTH, 0, stream>>>(x, Wh, Wx, out, xch);
}